// Round 5
// baseline (109.873 us; speedup 1.0000x reference)
//
#include <hip/hip_runtime.h>
#include <utility>

// ============================================================================
// Compile-time Clebsch-Gordan coefficients (port of the e3nn-convention math
// from the reference). All evaluated by the compiler; zeros fold away.
// ============================================================================
namespace cgc {

constexpr double cfact(int n) {
    double r = 1.0;
    for (int i = 2; i <= n; ++i) r *= (double)i;
    return r;
}

constexpr double csqrt(double x) {
    if (x <= 0.0) return 0.0;
    double g = x > 1.0 ? x : 1.0;
    for (int it = 0; it < 64; ++it) {
        double ng = 0.5 * (g + x / g);
        if (ng == g) break;
        g = ng;
    }
    return g;
}

struct cplx { double re; double im; };
constexpr cplx cadd(cplx a, cplx b) { return {a.re + b.re, a.im + b.im}; }
constexpr cplx cmul(cplx a, cplx b) {
    return {a.re * b.re - a.im * b.im, a.re * b.im + a.im * b.re};
}
constexpr cplx cconj(cplx a) { return {a.re, -a.im}; }

constexpr double su2_cg_coef(int j1, int m1, int j2, int m2, int j3, int m3) {
    double pref = csqrt((2.0 * j3 + 1.0) * cfact(j3 + j1 - j2) * cfact(j3 - j1 + j2) *
                        cfact(j1 + j2 - j3) / cfact(j1 + j2 + j3 + 1));
    pref *= csqrt(cfact(j3 + m3) * cfact(j3 - m3) * cfact(j1 - m1) * cfact(j1 + m1) *
                  cfact(j2 - m2) * cfact(j2 + m2));
    double s = 0.0;
    for (int k = 0; k <= j1 + j2 - j3; ++k) {
        int d0 = k, d1 = j1 + j2 - j3 - k, d2 = j1 - m1 - k;
        int d3 = j2 + m2 - k, d4 = j3 - j2 + m1 + k, d5 = j3 - j1 - m2 + k;
        if (d0 < 0 || d1 < 0 || d2 < 0 || d3 < 0 || d4 < 0 || d5 < 0) continue;
        double denom = cfact(d0) * cfact(d1) * cfact(d2) * cfact(d3) * cfact(d4) * cfact(d5);
        s += ((k & 1) ? -1.0 : 1.0) / denom;
    }
    return pref * s;
}

struct T3  { double v[5][5][5]; };
struct M2  { cplx v[5][5]; };
struct CT3 { cplx v[5][5][5]; };

constexpr T3 su2_cg(int j1, int j2, int j3) {
    T3 C{};
    for (int m1 = -j1; m1 <= j1; ++m1)
        for (int m2 = -j2; m2 <= j2; ++m2) {
            int m3 = m1 + m2;
            if (m3 >= -j3 && m3 <= j3)
                C.v[j1 + m1][j2 + m2][j3 + m3] = su2_cg_coef(j1, m1, j2, m2, j3, m3);
        }
    return C;
}

constexpr M2 real_to_complex(int l) {
    M2 q{};
    const double s = csqrt(0.5);
    for (int m = -l; m < 0; ++m) {
        q.v[l + m][l - m] = cplx{s, 0.0};
        q.v[l + m][l + m] = cplx{0.0, -s};
    }
    q.v[l][l] = cplx{1.0, 0.0};
    for (int m = 1; m <= l; ++m) {
        double sg = (m & 1) ? -1.0 : 1.0;
        q.v[l + m][l + m] = cplx{sg * s, 0.0};
        q.v[l + m][l - m] = cplx{0.0, sg * s};
    }
    cplx ph{1.0, 0.0};
    for (int i = 0; i < l; ++i) ph = cmul(ph, cplx{0.0, -1.0});  // (-1j)^l
    for (int r = 0; r < 2 * l + 1; ++r)
        for (int c = 0; c < 2 * l + 1; ++c)
            q.v[r][c] = cmul(q.v[r][c], ph);
    return q;
}

constexpr T3 so3_cg(int l1, int l2, int l3) {
    M2 Q1 = real_to_complex(l1);
    M2 Q2 = real_to_complex(l2);
    M2 Q3 = real_to_complex(l3);
    T3 Cs = su2_cg(l1, l2, l3);
    int n1 = 2 * l1 + 1, n2 = 2 * l2 + 1, n3 = 2 * l3 + 1;
    CT3 t1{};
    for (int j = 0; j < n1; ++j)
        for (int k = 0; k < n2; ++k)
            for (int n = 0; n < n3; ++n) {
                cplx acc{0.0, 0.0};
                for (int i = 0; i < n1; ++i)
                    acc = cadd(acc, cmul(Q1.v[i][j], cplx{Cs.v[i][k][n], 0.0}));
                t1.v[j][k][n] = acc;
            }
    CT3 t2{};
    for (int j = 0; j < n1; ++j)
        for (int L = 0; L < n2; ++L)
            for (int n = 0; n < n3; ++n) {
                cplx acc{0.0, 0.0};
                for (int k = 0; k < n2; ++k)
                    acc = cadd(acc, cmul(Q2.v[k][L], t1.v[j][k][n]));
                t2.v[j][L][n] = acc;
            }
    T3 R{};
    double norm2 = 0.0;
    for (int j = 0; j < n1; ++j)
        for (int L = 0; L < n2; ++L)
            for (int m = 0; m < n3; ++m) {
                cplx acc{0.0, 0.0};
                for (int n = 0; n < n3; ++n)
                    acc = cadd(acc, cmul(cconj(Q3.v[n][m]), t2.v[j][L][n]));
                R.v[j][L][m] = acc.re;
                norm2 += acc.re * acc.re;
            }
    double nrm = csqrt(norm2);
    if (nrm > 0.0)
        for (int j = 0; j < n1; ++j)
            for (int L = 0; L < n2; ++L)
                for (int m = 0; m < n3; ++m)
                    R.v[j][L][m] /= nrm;
    return R;
}

template <int LA, int LH, int LO>
constexpr T3 CGT = so3_cg(LA, LH, LO);

}  // namespace cgc

// ============================================================================
// Device side
// ============================================================================
template <typename F, int... Is>
__device__ __forceinline__ void unroll_impl(F&& f, std::integer_sequence<int, Is...>) {
    (f(std::integral_constant<int, Is>{}), ...);
}
template <int N, typename F>
__device__ __forceinline__ void unroll(F&& f) {
    unroll_impl(static_cast<F&&>(f), std::make_integer_sequence<int, N>{});
}

// o[k] += w * sum_{i,j} C[i][j][k] * a[i] * h[j], zeros folded at compile time.
template <int LA, int LH, int LO>
__device__ __forceinline__ void combo(float w, const float* a, const float* h, float* o) {
    constexpr int DA = 2 * LA + 1, DH = 2 * LH + 1, DO = 2 * LO + 1;
    unroll<DO>([&](auto kc) {
        constexpr int k = decltype(kc)::value;
        float s = 0.f;
        unroll<DA * DH>([&](auto tc) {
            constexpr int t = decltype(tc)::value;
            constexpr int i = t / DH;
            constexpr int j = t % DH;
            constexpr double cd = cgc::CGT<LA, LH, LO>.v[i][j][k];
            if constexpr (cd > 1e-12 || cd < -1e-12) {
                constexpr float c = (float)cd;
                s = fmaf(c, a[i] * h[j], s);
            }
        });
        o[k] = fmaf(w, s, o[k]);
    });
}

__device__ __forceinline__ void compute_edge(const float* a, const float* h,
                                             const float* W0, const float* W1,
                                             const float* W2, float* o) {
#pragma unroll
    for (int k = 0; k < 9; ++k) o[k] = 0.f;
    // combo order == Python _valid_combos order (ai outer, hi inner)
    combo<0, 0, 0>(W0[0], a + 0, h + 0, o + 0);
    combo<1, 1, 0>(W0[1], a + 1, h + 1, o + 0);
    combo<2, 2, 0>(W0[2], a + 4, h + 4, o + 0);
    combo<0, 1, 1>(W1[0], a + 0, h + 1, o + 1);
    combo<1, 0, 1>(W1[1], a + 1, h + 0, o + 1);
    combo<1, 1, 1>(W1[2], a + 1, h + 1, o + 1);
    combo<1, 2, 1>(W1[3], a + 1, h + 4, o + 1);
    combo<2, 1, 1>(W1[4], a + 4, h + 1, o + 1);
    combo<2, 2, 1>(W1[5], a + 4, h + 4, o + 1);
    combo<0, 2, 2>(W2[0], a + 0, h + 4, o + 4);
    combo<1, 1, 2>(W2[1], a + 1, h + 1, o + 4);
    combo<1, 2, 2>(W2[2], a + 1, h + 4, o + 4);
    combo<2, 0, 2>(W2[3], a + 4, h + 0, o + 4);
    combo<2, 1, 2>(W2[4], a + 4, h + 1, o + 4);
    combo<2, 2, 2>(W2[5], a + 4, h + 4, o + 4);
}

// Two edges per thread: all loads become float2 (every pair-row starts at an
// even float offset), cutting VMEM load instructions 3x per edge, and each
// thread carries two independent FMA chains (2x ILP). Stores stay LDS-staged
// (proven +) with a dense dword scatter.
__global__ __launch_bounds__(256, 6) void gnn_pair(
    const float* __restrict__ a0, const float* __restrict__ a1, const float* __restrict__ a2,
    const float* __restrict__ h0, const float* __restrict__ h1, const float* __restrict__ h2,
    const float* __restrict__ w0, const float* __restrict__ w1, const float* __restrict__ w2,
    float* __restrict__ out, int E) {
    const int t = threadIdx.x;
    const size_t base = (size_t)blockIdx.x * 512;
    long long remll = (long long)E - (long long)base;
    const int nE = remll > 512 ? 512 : (remll > 0 ? (int)remll : 0);

    __shared__ float s[4608];  // 18432 B: 512 edges x 9

    // wave-uniform weight loads -> scalarized
    float W0[3], W1[6], W2[6];
#pragma unroll
    for (int i = 0; i < 3; ++i) W0[i] = w0[i];
#pragma unroll
    for (int i = 0; i < 6; ++i) W1[i] = w1[i];
#pragma unroll
    for (int i = 0; i < 6; ++i) W2[i] = w2[i];

    const int e2 = 2 * t;
    if (e2 + 1 < nE) {
        const size_t ep = base + e2;  // even
        // ---- paired float2 loads (all 8B-aligned) ----
        float2 A0 = *(const float2*)(a0 + ep);
        float2 H0 = *(const float2*)(h0 + ep);
        float2 A1[3], H1[3], A2[5], H2[5];
        {
            const float2* p = (const float2*)(a1 + 3 * ep);
#pragma unroll
            for (int c = 0; c < 3; ++c) A1[c] = p[c];
        }
        {
            const float2* p = (const float2*)(h1 + 3 * ep);
#pragma unroll
            for (int c = 0; c < 3; ++c) H1[c] = p[c];
        }
        {
            const float2* p = (const float2*)(a2 + 5 * ep);
#pragma unroll
            for (int c = 0; c < 5; ++c) A2[c] = p[c];
        }
        {
            const float2* p = (const float2*)(h2 + 5 * ep);
#pragma unroll
            for (int c = 0; c < 5; ++c) H2[c] = p[c];
        }

        // ---- unpack: edge0 = first halves, edge1 = second halves ----
        float aE0[9] = {A0.x, A1[0].x, A1[0].y, A1[1].x,
                        A2[0].x, A2[0].y, A2[1].x, A2[1].y, A2[2].x};
        float aE1[9] = {A0.y, A1[1].y, A1[2].x, A1[2].y,
                        A2[2].y, A2[3].x, A2[3].y, A2[4].x, A2[4].y};
        float hE0[9] = {H0.x, H1[0].x, H1[0].y, H1[1].x,
                        H2[0].x, H2[0].y, H2[1].x, H2[1].y, H2[2].x};
        float hE1[9] = {H0.y, H1[1].y, H1[2].x, H1[2].y,
                        H2[2].y, H2[3].x, H2[3].y, H2[4].x, H2[4].y};

        float o0[9], o1[9];
        compute_edge(aE0, hE0, W0, W1, W2, o0);
        compute_edge(aE1, hE1, W0, W1, W2, o1);

#pragma unroll
        for (int k = 0; k < 9; ++k) s[18 * t + k] = o0[k];
#pragma unroll
        for (int k = 0; k < 9; ++k) s[18 * t + 9 + k] = o1[k];
    } else if (e2 < nE) {
        // odd tail edge (not hit for E = 2,000,000; kept correct)
        const size_t es = base + e2;
        float a[9], h[9], o[9];
        a[0] = a0[es];
#pragma unroll
        for (int c = 0; c < 3; ++c) a[1 + c] = a1[3 * es + c];
#pragma unroll
        for (int c = 0; c < 5; ++c) a[4 + c] = a2[5 * es + c];
        h[0] = h0[es];
#pragma unroll
        for (int c = 0; c < 3; ++c) h[1 + c] = h1[3 * es + c];
#pragma unroll
        for (int c = 0; c < 5; ++c) h[4 + c] = h2[5 * es + c];
        compute_edge(a, h, W0, W1, W2, o);
#pragma unroll
        for (int k = 0; k < 9; ++k) s[18 * t + k] = o[k];
    }
    __syncthreads();

    // ---- dense scatter: lane-contiguous dwords ----
    const int n9 = 9 * nE;
#pragma unroll
    for (int c = 0; c < 18; ++c) {
        int i = c * 256 + t;
        if (i < n9) out[9 * base + i] = s[i];
    }
}

extern "C" void kernel_launch(void* const* d_in, const int* in_sizes, int n_in,
                              void* d_out, int out_size, void* d_ws, size_t ws_size,
                              hipStream_t stream) {
    (void)n_in; (void)d_ws; (void)ws_size; (void)out_size;
    const float *a0, *a1, *a2, *h0, *h1, *h2;
    // setup_inputs() dict order interleaves: a0,h0,a1,h1,a2,h2. Detect by sizes
    // in case the harness used the reference-signature order instead.
    if (in_sizes[1] == in_sizes[0]) {
        a0 = (const float*)d_in[0]; h0 = (const float*)d_in[1];
        a1 = (const float*)d_in[2]; h1 = (const float*)d_in[3];
        a2 = (const float*)d_in[4]; h2 = (const float*)d_in[5];
    } else {
        a0 = (const float*)d_in[0]; a1 = (const float*)d_in[1];
        a2 = (const float*)d_in[2]; h0 = (const float*)d_in[3];
        h1 = (const float*)d_in[4]; h2 = (const float*)d_in[5];
    }
    const float* w0 = (const float*)d_in[6];
    const float* w1 = (const float*)d_in[7];
    const float* w2 = (const float*)d_in[8];
    float* out = (float*)d_out;

    int E = in_sizes[0];
    int blocks = (E + 511) / 512;
    gnn_pair<<<blocks, 256, 0, stream>>>(a0, a1, a2, h0, h1, h2, w0, w1, w2, out, E);
}

// Round 6
// 38.667 us; speedup vs baseline: 2.8416x; 2.8416x over previous
//
#include <hip/hip_runtime.h>
#include <utility>

// ============================================================================
// Compile-time Clebsch-Gordan coefficients (port of the e3nn-convention math
// from the reference). All evaluated by the compiler; zeros fold away.
// ============================================================================
namespace cgc {

constexpr double cfact(int n) {
    double r = 1.0;
    for (int i = 2; i <= n; ++i) r *= (double)i;
    return r;
}

constexpr double csqrt(double x) {
    if (x <= 0.0) return 0.0;
    double g = x > 1.0 ? x : 1.0;
    for (int it = 0; it < 64; ++it) {
        double ng = 0.5 * (g + x / g);
        if (ng == g) break;
        g = ng;
    }
    return g;
}

struct cplx { double re; double im; };
constexpr cplx cadd(cplx a, cplx b) { return {a.re + b.re, a.im + b.im}; }
constexpr cplx cmul(cplx a, cplx b) {
    return {a.re * b.re - a.im * b.im, a.re * b.im + a.im * b.re};
}
constexpr cplx cconj(cplx a) { return {a.re, -a.im}; }

constexpr double su2_cg_coef(int j1, int m1, int j2, int m2, int j3, int m3) {
    double pref = csqrt((2.0 * j3 + 1.0) * cfact(j3 + j1 - j2) * cfact(j3 - j1 + j2) *
                        cfact(j1 + j2 - j3) / cfact(j1 + j2 + j3 + 1));
    pref *= csqrt(cfact(j3 + m3) * cfact(j3 - m3) * cfact(j1 - m1) * cfact(j1 + m1) *
                  cfact(j2 - m2) * cfact(j2 + m2));
    double s = 0.0;
    for (int k = 0; k <= j1 + j2 - j3; ++k) {
        int d0 = k, d1 = j1 + j2 - j3 - k, d2 = j1 - m1 - k;
        int d3 = j2 + m2 - k, d4 = j3 - j2 + m1 + k, d5 = j3 - j1 - m2 + k;
        if (d0 < 0 || d1 < 0 || d2 < 0 || d3 < 0 || d4 < 0 || d5 < 0) continue;
        double denom = cfact(d0) * cfact(d1) * cfact(d2) * cfact(d3) * cfact(d4) * cfact(d5);
        s += ((k & 1) ? -1.0 : 1.0) / denom;
    }
    return pref * s;
}

struct T3  { double v[5][5][5]; };
struct M2  { cplx v[5][5]; };
struct CT3 { cplx v[5][5][5]; };

constexpr T3 su2_cg(int j1, int j2, int j3) {
    T3 C{};
    for (int m1 = -j1; m1 <= j1; ++m1)
        for (int m2 = -j2; m2 <= j2; ++m2) {
            int m3 = m1 + m2;
            if (m3 >= -j3 && m3 <= j3)
                C.v[j1 + m1][j2 + m2][j3 + m3] = su2_cg_coef(j1, m1, j2, m2, j3, m3);
        }
    return C;
}

constexpr M2 real_to_complex(int l) {
    M2 q{};
    const double s = csqrt(0.5);
    for (int m = -l; m < 0; ++m) {
        q.v[l + m][l - m] = cplx{s, 0.0};
        q.v[l + m][l + m] = cplx{0.0, -s};
    }
    q.v[l][l] = cplx{1.0, 0.0};
    for (int m = 1; m <= l; ++m) {
        double sg = (m & 1) ? -1.0 : 1.0;
        q.v[l + m][l + m] = cplx{sg * s, 0.0};
        q.v[l + m][l - m] = cplx{0.0, sg * s};
    }
    cplx ph{1.0, 0.0};
    for (int i = 0; i < l; ++i) ph = cmul(ph, cplx{0.0, -1.0});  // (-1j)^l
    for (int r = 0; r < 2 * l + 1; ++r)
        for (int c = 0; c < 2 * l + 1; ++c)
            q.v[r][c] = cmul(q.v[r][c], ph);
    return q;
}

constexpr T3 so3_cg(int l1, int l2, int l3) {
    M2 Q1 = real_to_complex(l1);
    M2 Q2 = real_to_complex(l2);
    M2 Q3 = real_to_complex(l3);
    T3 Cs = su2_cg(l1, l2, l3);
    int n1 = 2 * l1 + 1, n2 = 2 * l2 + 1, n3 = 2 * l3 + 1;
    CT3 t1{};
    for (int j = 0; j < n1; ++j)
        for (int k = 0; k < n2; ++k)
            for (int n = 0; n < n3; ++n) {
                cplx acc{0.0, 0.0};
                for (int i = 0; i < n1; ++i)
                    acc = cadd(acc, cmul(Q1.v[i][j], cplx{Cs.v[i][k][n], 0.0}));
                t1.v[j][k][n] = acc;
            }
    CT3 t2{};
    for (int j = 0; j < n1; ++j)
        for (int L = 0; L < n2; ++L)
            for (int n = 0; n < n3; ++n) {
                cplx acc{0.0, 0.0};
                for (int k = 0; k < n2; ++k)
                    acc = cadd(acc, cmul(Q2.v[k][L], t1.v[j][k][n]));
                t2.v[j][L][n] = acc;
            }
    T3 R{};
    double norm2 = 0.0;
    for (int j = 0; j < n1; ++j)
        for (int L = 0; L < n2; ++L)
            for (int m = 0; m < n3; ++m) {
                cplx acc{0.0, 0.0};
                for (int n = 0; n < n3; ++n)
                    acc = cadd(acc, cmul(cconj(Q3.v[n][m]), t2.v[j][L][n]));
                R.v[j][L][m] = acc.re;
                norm2 += acc.re * acc.re;
            }
    double nrm = csqrt(norm2);
    if (nrm > 0.0)
        for (int j = 0; j < n1; ++j)
            for (int L = 0; L < n2; ++L)
                for (int m = 0; m < n3; ++m)
                    R.v[j][L][m] /= nrm;
    return R;
}

template <int LA, int LH, int LO>
constexpr T3 CGT = so3_cg(LA, LH, LO);

}  // namespace cgc

// ============================================================================
// Device side
// ============================================================================
template <typename F, int... Is>
__device__ __forceinline__ void unroll_impl(F&& f, std::integer_sequence<int, Is...>) {
    (f(std::integral_constant<int, Is>{}), ...);
}
template <int N, typename F>
__device__ __forceinline__ void unroll(F&& f) {
    unroll_impl(static_cast<F&&>(f), std::make_integer_sequence<int, N>{});
}

// o[k] += w * sum_{i,j} C[i][j][k] * a[i] * h[j], zeros folded at compile time.
template <int LA, int LH, int LO>
__device__ __forceinline__ void combo(float w, const float* a, const float* h, float* o) {
    constexpr int DA = 2 * LA + 1, DH = 2 * LH + 1, DO = 2 * LO + 1;
    unroll<DO>([&](auto kc) {
        constexpr int k = decltype(kc)::value;
        float s = 0.f;
        unroll<DA * DH>([&](auto tc) {
            constexpr int t = decltype(tc)::value;
            constexpr int i = t / DH;
            constexpr int j = t % DH;
            constexpr double cd = cgc::CGT<LA, LH, LO>.v[i][j][k];
            if constexpr (cd > 1e-12 || cd < -1e-12) {
                constexpr float c = (float)cd;
                s = fmaf(c, a[i] * h[j], s);
            }
        });
        o[k] = fmaf(w, s, o[k]);
    });
}

__device__ __forceinline__ void compute_edge(const float* a, const float* h,
                                             const float* W0, const float* W1,
                                             const float* W2, float* o) {
#pragma unroll
    for (int k = 0; k < 9; ++k) o[k] = 0.f;
    // combo order == Python _valid_combos order (ai outer, hi inner)
    combo<0, 0, 0>(W0[0], a + 0, h + 0, o + 0);
    combo<1, 1, 0>(W0[1], a + 1, h + 1, o + 0);
    combo<2, 2, 0>(W0[2], a + 4, h + 4, o + 0);
    combo<0, 1, 1>(W1[0], a + 0, h + 1, o + 1);
    combo<1, 0, 1>(W1[1], a + 1, h + 0, o + 1);
    combo<1, 1, 1>(W1[2], a + 1, h + 1, o + 1);
    combo<1, 2, 1>(W1[3], a + 1, h + 4, o + 1);
    combo<2, 1, 1>(W1[4], a + 4, h + 1, o + 1);
    combo<2, 2, 1>(W1[5], a + 4, h + 4, o + 1);
    combo<0, 2, 2>(W2[0], a + 0, h + 4, o + 4);
    combo<1, 1, 2>(W2[1], a + 1, h + 1, o + 4);
    combo<1, 2, 2>(W2[2], a + 1, h + 4, o + 4);
    combo<2, 0, 2>(W2[3], a + 4, h + 0, o + 4);
    combo<2, 1, 2>(W2[4], a + 4, h + 1, o + 4);
    combo<2, 2, 2>(W2[5], a + 4, h + 4, o + 4);
}

// Two edges per thread, float2 loads (9 VMEM instr/edge vs 27), two
// independent FMA chains, LDS-staged dense stores. NO min-occupancy pin:
// R5 proved __launch_bounds__(256,6)'s 40-VGPR cap spills the whole working
// set to scratch (FETCH 70->210 MB, WRITE 70->241 MB). Let the compiler
// take ~64-90 VGPRs; ~50% occupancy was sufficient in R2/R4.
__global__ __launch_bounds__(256) void gnn_pair2(
    const float* __restrict__ a0, const float* __restrict__ a1, const float* __restrict__ a2,
    const float* __restrict__ h0, const float* __restrict__ h1, const float* __restrict__ h2,
    const float* __restrict__ w0, const float* __restrict__ w1, const float* __restrict__ w2,
    float* __restrict__ out, int E) {
    const int t = threadIdx.x;
    const size_t base = (size_t)blockIdx.x * 512;
    long long remll = (long long)E - (long long)base;
    const int nE = remll > 512 ? 512 : (remll > 0 ? (int)remll : 0);

    __shared__ float s[4608];  // 18432 B: 512 edges x 9

    // wave-uniform weight loads -> scalarized
    float W0[3], W1[6], W2[6];
#pragma unroll
    for (int i = 0; i < 3; ++i) W0[i] = w0[i];
#pragma unroll
    for (int i = 0; i < 6; ++i) W1[i] = w1[i];
#pragma unroll
    for (int i = 0; i < 6; ++i) W2[i] = w2[i];

    const int e2 = 2 * t;
    if (e2 + 1 < nE) {
        const size_t ep = base + e2;  // even
        // ---- paired float2 loads (all 8B-aligned) ----
        float2 A0 = *(const float2*)(a0 + ep);
        float2 H0 = *(const float2*)(h0 + ep);
        float2 A1[3], H1[3], A2[5], H2[5];
        {
            const float2* p = (const float2*)(a1 + 3 * ep);
#pragma unroll
            for (int c = 0; c < 3; ++c) A1[c] = p[c];
        }
        {
            const float2* p = (const float2*)(h1 + 3 * ep);
#pragma unroll
            for (int c = 0; c < 3; ++c) H1[c] = p[c];
        }
        {
            const float2* p = (const float2*)(a2 + 5 * ep);
#pragma unroll
            for (int c = 0; c < 5; ++c) A2[c] = p[c];
        }
        {
            const float2* p = (const float2*)(h2 + 5 * ep);
#pragma unroll
            for (int c = 0; c < 5; ++c) H2[c] = p[c];
        }

        // ---- unpack: edge0 = first halves, edge1 = second halves ----
        float aE0[9] = {A0.x, A1[0].x, A1[0].y, A1[1].x,
                        A2[0].x, A2[0].y, A2[1].x, A2[1].y, A2[2].x};
        float aE1[9] = {A0.y, A1[1].y, A1[2].x, A1[2].y,
                        A2[2].y, A2[3].x, A2[3].y, A2[4].x, A2[4].y};
        float hE0[9] = {H0.x, H1[0].x, H1[0].y, H1[1].x,
                        H2[0].x, H2[0].y, H2[1].x, H2[1].y, H2[2].x};
        float hE1[9] = {H0.y, H1[1].y, H1[2].x, H1[2].y,
                        H2[2].y, H2[3].x, H2[3].y, H2[4].x, H2[4].y};

        float o0[9], o1[9];
        compute_edge(aE0, hE0, W0, W1, W2, o0);
        compute_edge(aE1, hE1, W0, W1, W2, o1);

#pragma unroll
        for (int k = 0; k < 9; ++k) s[18 * t + k] = o0[k];
#pragma unroll
        for (int k = 0; k < 9; ++k) s[18 * t + 9 + k] = o1[k];
    } else if (e2 < nE) {
        // odd tail edge (not hit for E = 2,000,000; kept correct)
        const size_t es = base + e2;
        float a[9], h[9], o[9];
        a[0] = a0[es];
#pragma unroll
        for (int c = 0; c < 3; ++c) a[1 + c] = a1[3 * es + c];
#pragma unroll
        for (int c = 0; c < 5; ++c) a[4 + c] = a2[5 * es + c];
        h[0] = h0[es];
#pragma unroll
        for (int c = 0; c < 3; ++c) h[1 + c] = h1[3 * es + c];
#pragma unroll
        for (int c = 0; c < 5; ++c) h[4 + c] = h2[5 * es + c];
        compute_edge(a, h, W0, W1, W2, o);
#pragma unroll
        for (int k = 0; k < 9; ++k) s[18 * t + k] = o[k];
    }
    __syncthreads();

    // ---- dense scatter: lane-contiguous dwords ----
    const int n9 = 9 * nE;
#pragma unroll
    for (int c = 0; c < 18; ++c) {
        int i = c * 256 + t;
        if (i < n9) out[9 * base + i] = s[i];
    }
}

extern "C" void kernel_launch(void* const* d_in, const int* in_sizes, int n_in,
                              void* d_out, int out_size, void* d_ws, size_t ws_size,
                              hipStream_t stream) {
    (void)n_in; (void)d_ws; (void)ws_size; (void)out_size;
    const float *a0, *a1, *a2, *h0, *h1, *h2;
    // setup_inputs() dict order interleaves: a0,h0,a1,h1,a2,h2. Detect by sizes
    // in case the harness used the reference-signature order instead.
    if (in_sizes[1] == in_sizes[0]) {
        a0 = (const float*)d_in[0]; h0 = (const float*)d_in[1];
        a1 = (const float*)d_in[2]; h1 = (const float*)d_in[3];
        a2 = (const float*)d_in[4]; h2 = (const float*)d_in[5];
    } else {
        a0 = (const float*)d_in[0]; a1 = (const float*)d_in[1];
        a2 = (const float*)d_in[2]; h0 = (const float*)d_in[3];
        h1 = (const float*)d_in[4]; h2 = (const float*)d_in[5];
    }
    const float* w0 = (const float*)d_in[6];
    const float* w1 = (const float*)d_in[7];
    const float* w2 = (const float*)d_in[8];
    float* out = (float*)d_out;

    int E = in_sizes[0];
    int blocks = (E + 511) / 512;
    gnn_pair2<<<blocks, 256, 0, stream>>>(a0, a1, a2, h0, h1, h2, w0, w1, w2, out, E);
}

// Round 8
// 36.508 us; speedup vs baseline: 3.0096x; 1.0591x over previous
//
#include <hip/hip_runtime.h>
#include <utility>

// ============================================================================
// Compile-time Clebsch-Gordan coefficients (port of the e3nn-convention math
// from the reference). All evaluated by the compiler; zeros fold away.
// ============================================================================
namespace cgc {

constexpr double cfact(int n) {
    double r = 1.0;
    for (int i = 2; i <= n; ++i) r *= (double)i;
    return r;
}

constexpr double csqrt(double x) {
    if (x <= 0.0) return 0.0;
    double g = x > 1.0 ? x : 1.0;
    for (int it = 0; it < 64; ++it) {
        double ng = 0.5 * (g + x / g);
        if (ng == g) break;
        g = ng;
    }
    return g;
}

struct cplx { double re; double im; };
constexpr cplx cadd(cplx a, cplx b) { return {a.re + b.re, a.im + b.im}; }
constexpr cplx cmul(cplx a, cplx b) {
    return {a.re * b.re - a.im * b.im, a.re * b.im + a.im * b.re};
}
constexpr cplx cconj(cplx a) { return {a.re, -a.im}; }

constexpr double su2_cg_coef(int j1, int m1, int j2, int m2, int j3, int m3) {
    double pref = csqrt((2.0 * j3 + 1.0) * cfact(j3 + j1 - j2) * cfact(j3 - j1 + j2) *
                        cfact(j1 + j2 - j3) / cfact(j1 + j2 + j3 + 1));
    pref *= csqrt(cfact(j3 + m3) * cfact(j3 - m3) * cfact(j1 - m1) * cfact(j1 + m1) *
                  cfact(j2 - m2) * cfact(j2 + m2));
    double s = 0.0;
    for (int k = 0; k <= j1 + j2 - j3; ++k) {
        int d0 = k, d1 = j1 + j2 - j3 - k, d2 = j1 - m1 - k;
        int d3 = j2 + m2 - k, d4 = j3 - j2 + m1 + k, d5 = j3 - j1 - m2 + k;
        if (d0 < 0 || d1 < 0 || d2 < 0 || d3 < 0 || d4 < 0 || d5 < 0) continue;
        double denom = cfact(d0) * cfact(d1) * cfact(d2) * cfact(d3) * cfact(d4) * cfact(d5);
        s += ((k & 1) ? -1.0 : 1.0) / denom;
    }
    return pref * s;
}

struct T3  { double v[5][5][5]; };
struct M2  { cplx v[5][5]; };
struct CT3 { cplx v[5][5][5]; };

constexpr T3 su2_cg(int j1, int j2, int j3) {
    T3 C{};
    for (int m1 = -j1; m1 <= j1; ++m1)
        for (int m2 = -j2; m2 <= j2; ++m2) {
            int m3 = m1 + m2;
            if (m3 >= -j3 && m3 <= j3)
                C.v[j1 + m1][j2 + m2][j3 + m3] = su2_cg_coef(j1, m1, j2, m2, j3, m3);
        }
    return C;
}

constexpr M2 real_to_complex(int l) {
    M2 q{};
    const double s = csqrt(0.5);
    for (int m = -l; m < 0; ++m) {
        q.v[l + m][l - m] = cplx{s, 0.0};
        q.v[l + m][l + m] = cplx{0.0, -s};
    }
    q.v[l][l] = cplx{1.0, 0.0};
    for (int m = 1; m <= l; ++m) {
        double sg = (m & 1) ? -1.0 : 1.0;
        q.v[l + m][l + m] = cplx{sg * s, 0.0};
        q.v[l + m][l - m] = cplx{0.0, sg * s};
    }
    cplx ph{1.0, 0.0};
    for (int i = 0; i < l; ++i) ph = cmul(ph, cplx{0.0, -1.0});  // (-1j)^l
    for (int r = 0; r < 2 * l + 1; ++r)
        for (int c = 0; c < 2 * l + 1; ++c)
            q.v[r][c] = cmul(q.v[r][c], ph);
    return q;
}

constexpr T3 so3_cg(int l1, int l2, int l3) {
    M2 Q1 = real_to_complex(l1);
    M2 Q2 = real_to_complex(l2);
    M2 Q3 = real_to_complex(l3);
    T3 Cs = su2_cg(l1, l2, l3);
    int n1 = 2 * l1 + 1, n2 = 2 * l2 + 1, n3 = 2 * l3 + 1;
    CT3 t1{};
    for (int j = 0; j < n1; ++j)
        for (int k = 0; k < n2; ++k)
            for (int n = 0; n < n3; ++n) {
                cplx acc{0.0, 0.0};
                for (int i = 0; i < n1; ++i)
                    acc = cadd(acc, cmul(Q1.v[i][j], cplx{Cs.v[i][k][n], 0.0}));
                t1.v[j][k][n] = acc;
            }
    CT3 t2{};
    for (int j = 0; j < n1; ++j)
        for (int L = 0; L < n2; ++L)
            for (int n = 0; n < n3; ++n) {
                cplx acc{0.0, 0.0};
                for (int k = 0; k < n2; ++k)
                    acc = cadd(acc, cmul(Q2.v[k][L], t1.v[j][k][n]));
                t2.v[j][L][n] = acc;
            }
    T3 R{};
    double norm2 = 0.0;
    for (int j = 0; j < n1; ++j)
        for (int L = 0; L < n2; ++L)
            for (int m = 0; m < n3; ++m) {
                cplx acc{0.0, 0.0};
                for (int n = 0; n < n3; ++n)
                    acc = cadd(acc, cmul(cconj(Q3.v[n][m]), t2.v[j][L][n]));
                R.v[j][L][m] = acc.re;
                norm2 += acc.re * acc.re;
            }
    double nrm = csqrt(norm2);
    if (nrm > 0.0)
        for (int j = 0; j < n1; ++j)
            for (int L = 0; L < n2; ++L)
                for (int m = 0; m < n3; ++m)
                    R.v[j][L][m] /= nrm;
    return R;
}

template <int LA, int LH, int LO>
constexpr T3 CGT = so3_cg(LA, LH, LO);

}  // namespace cgc

// ============================================================================
// Device side
// ============================================================================
typedef float f32x4 __attribute__((ext_vector_type(4)));  // native vector for nt builtins

template <typename F, int... Is>
__device__ __forceinline__ void unroll_impl(F&& f, std::integer_sequence<int, Is...>) {
    (f(std::integral_constant<int, Is>{}), ...);
}
template <int N, typename F>
__device__ __forceinline__ void unroll(F&& f) {
    unroll_impl(static_cast<F&&>(f), std::make_integer_sequence<int, N>{});
}

// o[k] += w * sum_{i,j} C[i][j][k] * a[i] * h[j], zeros folded at compile time.
template <int LA, int LH, int LO>
__device__ __forceinline__ void combo(float w, const float* a, const float* h, float* o) {
    constexpr int DA = 2 * LA + 1, DH = 2 * LH + 1, DO = 2 * LO + 1;
    unroll<DO>([&](auto kc) {
        constexpr int k = decltype(kc)::value;
        float s = 0.f;
        unroll<DA * DH>([&](auto tc) {
            constexpr int t = decltype(tc)::value;
            constexpr int i = t / DH;
            constexpr int j = t % DH;
            constexpr double cd = cgc::CGT<LA, LH, LO>.v[i][j][k];
            if constexpr (cd > 1e-12 || cd < -1e-12) {
                constexpr float c = (float)cd;
                s = fmaf(c, a[i] * h[j], s);
            }
        });
        o[k] = fmaf(w, s, o[k]);
    });
}

__device__ __forceinline__ void compute_edge(const float* a, const float* h,
                                             const float* W0, const float* W1,
                                             const float* W2, float* o) {
#pragma unroll
    for (int k = 0; k < 9; ++k) o[k] = 0.f;
    // combo order == Python _valid_combos order (ai outer, hi inner)
    combo<0, 0, 0>(W0[0], a + 0, h + 0, o + 0);
    combo<1, 1, 0>(W0[1], a + 1, h + 1, o + 0);
    combo<2, 2, 0>(W0[2], a + 4, h + 4, o + 0);
    combo<0, 1, 1>(W1[0], a + 0, h + 1, o + 1);
    combo<1, 0, 1>(W1[1], a + 1, h + 0, o + 1);
    combo<1, 1, 1>(W1[2], a + 1, h + 1, o + 1);
    combo<1, 2, 1>(W1[3], a + 1, h + 4, o + 1);
    combo<2, 1, 1>(W1[4], a + 4, h + 1, o + 1);
    combo<2, 2, 1>(W1[5], a + 4, h + 4, o + 1);
    combo<0, 2, 2>(W2[0], a + 0, h + 4, o + 4);
    combo<1, 1, 2>(W2[1], a + 1, h + 1, o + 4);
    combo<1, 2, 2>(W2[2], a + 1, h + 4, o + 4);
    combo<2, 0, 2>(W2[3], a + 4, h + 0, o + 4);
    combo<2, 1, 2>(W2[4], a + 4, h + 1, o + 4);
    combo<2, 2, 2>(W2[5], a + 4, h + 4, o + 4);
}

// R4 structure (direct scalar loads, LDS-staged stores) + two changes:
//  1) output stores are NON-TEMPORAL: the 72 MB/replay write stream no longer
//     evicts the 144 MB input set from the 256 MB L3 -> input re-reads become
//     L3 hits (lower miss latency, FETCH_SIZE -> ~0 steady-state).
//  2) dense scatter via 16B vectors (3 store instr/thread instead of 9).
__global__ __launch_bounds__(256) void gnn_edge_nt(
    const float* __restrict__ a0, const float* __restrict__ a1, const float* __restrict__ a2,
    const float* __restrict__ h0, const float* __restrict__ h1, const float* __restrict__ h2,
    const float* __restrict__ w0, const float* __restrict__ w1, const float* __restrict__ w2,
    float* __restrict__ out, int E) {
    const int t = threadIdx.x;
    const size_t base = (size_t)blockIdx.x * 256;
    long long remll = (long long)E - (long long)base;
    const int nE = remll > 256 ? 256 : (remll > 0 ? (int)remll : 0);

    __shared__ float s[2304];  // 9216 B

    // wave-uniform weight loads -> scalarized
    float W0[3], W1[6], W2[6];
#pragma unroll
    for (int i = 0; i < 3; ++i) W0[i] = w0[i];
#pragma unroll
    for (int i = 0; i < 6; ++i) W1[i] = w1[i];
#pragma unroll
    for (int i = 0; i < 6; ++i) W2[i] = w2[i];

    if (t < nE) {
        size_t es = base + t;
        float a[9], h[9], o[9];
        a[0] = a0[es];
        {
            const float* p = a1 + 3 * es;
#pragma unroll
            for (int c = 0; c < 3; ++c) a[1 + c] = p[c];
        }
        {
            const float* p = a2 + 5 * es;
#pragma unroll
            for (int c = 0; c < 5; ++c) a[4 + c] = p[c];
        }
        h[0] = h0[es];
        {
            const float* p = h1 + 3 * es;
#pragma unroll
            for (int c = 0; c < 3; ++c) h[1 + c] = p[c];
        }
        {
            const float* p = h2 + 5 * es;
#pragma unroll
            for (int c = 0; c < 5; ++c) h[4 + c] = p[c];
        }

        compute_edge(a, h, W0, W1, W2, o);

#pragma unroll
        for (int k = 0; k < 9; ++k) s[9 * t + k] = o[k];  // stride 9: free 2-way aliasing
    }
    __syncthreads();

    if (nE == 256) {
        // full block: 2304 floats = 576 16B-vectors, aligned (9*base % 4 == 0)
        const f32x4* s4 = (const f32x4*)s;
        f32x4* o4 = (f32x4*)(out + 9 * base);
#pragma unroll
        for (int c = 0; c < 3; ++c) {
            int i = c * 256 + t;
            if (i < 576) __builtin_nontemporal_store(s4[i], o4 + i);
        }
    } else {
        const int n9 = 9 * nE;
#pragma unroll
        for (int c = 0; c < 9; ++c) {
            int i = c * 256 + t;
            if (i < n9) __builtin_nontemporal_store(s[i], out + 9 * base + i);
        }
    }
}

extern "C" void kernel_launch(void* const* d_in, const int* in_sizes, int n_in,
                              void* d_out, int out_size, void* d_ws, size_t ws_size,
                              hipStream_t stream) {
    (void)n_in; (void)d_ws; (void)ws_size; (void)out_size;
    const float *a0, *a1, *a2, *h0, *h1, *h2;
    // setup_inputs() dict order interleaves: a0,h0,a1,h1,a2,h2. Detect by sizes
    // in case the harness used the reference-signature order instead.
    if (in_sizes[1] == in_sizes[0]) {
        a0 = (const float*)d_in[0]; h0 = (const float*)d_in[1];
        a1 = (const float*)d_in[2]; h1 = (const float*)d_in[3];
        a2 = (const float*)d_in[4]; h2 = (const float*)d_in[5];
    } else {
        a0 = (const float*)d_in[0]; a1 = (const float*)d_in[1];
        a2 = (const float*)d_in[2]; h0 = (const float*)d_in[3];
        h1 = (const float*)d_in[4]; h2 = (const float*)d_in[5];
    }
    const float* w0 = (const float*)d_in[6];
    const float* w1 = (const float*)d_in[7];
    const float* w2 = (const float*)d_in[8];
    float* out = (float*)d_out;

    int E = in_sizes[0];
    int blocks = (E + 255) / 256;
    gnn_edge_nt<<<blocks, 256, 0, stream>>>(a0, a1, a2, h0, h1, h2, w0, w1, w2, out, E);
}